// Round 5
// baseline (1021.671 us; speedup 1.0000x reference)
//
#include <hip/hip_runtime.h>

#define C_   256
#define CR_  64
#define HW_  3136
#define W_   56
#define H_   56
#define NK_  144   // K*K*G

// span_w [144][64] -> swT2 [8][64][18]: swT2[wv][rr][kk] = sw[wv*18+kk][rr]
// Per-wave rows are 18 consecutive dwords -> s_load_dwordx16 runs. 36 864 B.
__global__ __launch_bounds__(256)
void repack_sw(const float* __restrict__ sw, float* __restrict__ swT2) {
    int idx = blockIdx.x * 256 + threadIdx.x;   // 9216 total
    int k  = idx / CR_;          // 0..143
    int rr = idx - k * CR_;      // 0..63
    int wv = k / 18, kk = k - wv * 18;
    swT2[(wv * CR_ + rr) * 18 + kk] = sw[idx];
}

// One block = 64 pixels, 8 waves. Phase A: wave (rr-quarter, c-half) computes
// 16 partial r-rows over 128 channels. Phase B: wave wv computes ker rows
// [wv*18, wv*18+18). Phase C: 9-tap involution, 32 chans/wave.
// ALL loops indexing register arrays are fully unrolled (rule #20: runtime
// indices send arrays to scratch -- round 3's 150 MB write bug).
__global__ __launch_bounds__(512, 4)
void inv_fused(const float* __restrict__ x, const float* __restrict__ rw,
               const float* __restrict__ swT2, const float* __restrict__ span_b,
               float* __restrict__ out) {
    __shared__ float rpart[2][CR_][64];   // [c-half][rr][pixel], 32 KiB

    const int b    = blockIdx.x / 49;
    const int tile = blockIdx.x % 49;
    const int wv   = threadIdx.x >> 6;
    const int lane = threadIdx.x & 63;
    const int hw   = tile * 64 + lane;
    const int h    = hw / W_;
    const int w    = hw - h * W_;
    const float* xb = x + (size_t)b * C_ * HW_;

    // Wave-uniform SGPR values -> weight reads ride the scalar pipe.
    const int rr0 = __builtin_amdgcn_readfirstlane((wv >> 1) * 16);
    const int c0  = __builtin_amdgcn_readfirstlane((wv & 1) * 128);
    const int ch  = wv & 1;

    // ---------- phase A: partial r (16 rr-rows over 128 channels) ----------
    float racc[16];
    #pragma unroll
    for (int j = 0; j < 16; ++j) racc[j] = 0.f;

    for (int i = 0; i < 128; i += 8) {
        float xv[8];                                   // 8 loads in flight
        #pragma unroll
        for (int u = 0; u < 8; ++u)
            xv[u] = xb[(size_t)(c0 + i + u) * HW_ + hw];   // coalesced 256B/wave
        #pragma unroll
        for (int j = 0; j < 16; ++j) {
            const float* wr = rw + (size_t)(rr0 + j) * C_ + c0 + i;  // uniform -> s_load
            #pragma unroll
            for (int u = 0; u < 8; ++u)
                racc[j] += wr[u] * xv[u];              // v_fmac, SGPR weight operand
        }
    }
    #pragma unroll
    for (int j = 0; j < 16; ++j)
        rpart[ch][rr0 + j][lane] = racc[j];
    __syncthreads();

    // ---------- phase B: ker[18] = swT2[wv] . (rpart0+rpart1) + b ----------
    const int k0 = __builtin_amdgcn_readfirstlane(wv * 18);
    float acc[18];
    #pragma unroll
    for (int k = 0; k < 18; ++k) acc[k] = span_b[k0 + k];

    const float* swv = swT2 + (size_t)wv * CR_ * 18;     // uniform base
    #pragma unroll                                       // FULL unroll: static r idx
    for (int rr = 0; rr < CR_; ++rr) {
        const float rv = rpart[0][rr][lane] + rpart[1][rr][lane];
        const float* wr = swv + rr * 18;                 // 18 consecutive dwords
        #pragma unroll
        for (int k = 0; k < 18; ++k)
            acc[k] += wr[k] * rv;                        // 18 independent chains
    }

    // ---------- phase C: 9-tap involution for 32 channels ----------
    const bool hok0 = (h > 0), hok2 = (h < H_ - 1);
    const bool wok0 = (w > 0), wok2 = (w < W_ - 1);

    #pragma unroll
    for (int gi = 0; gi < 2; ++gi) {
        #pragma unroll 4
        for (int cg = 0; cg < 16; ++cg) {
            const int c = (wv * 2 + gi) * 16 + cg;
            const float* xc = xb + (size_t)c * HW_ + hw;
            float a = 0.f;
            #pragma unroll
            for (int k = 0; k < 9; ++k) {
                const int di = k / 3 - 1, dj = k % 3 - 1;
                const bool ok = (di < 0 ? hok0 : (di > 0 ? hok2 : true))
                             && (dj < 0 ? wok0 : (dj > 0 ? wok2 : true));
                if (ok) a += acc[gi * 9 + k] * xc[di * W_ + dj];
            }
            out[((size_t)b * C_ + c) * HW_ + hw] = a;    // coalesced store
        }
    }
}

extern "C" void kernel_launch(void* const* d_in, const int* in_sizes, int n_in,
                              void* d_out, int out_size, void* d_ws, size_t ws_size,
                              hipStream_t stream) {
    const float* x  = (const float*)d_in[0];
    const float* rw = (const float*)d_in[1];  // [64][256]
    const float* sw = (const float*)d_in[2];  // [144][64]
    const float* sb = (const float*)d_in[3];  // [144]
    float* out  = (float*)d_out;
    float* swT2 = (float*)d_ws;               // 36 864 B

    repack_sw<<<36, 256, 0, stream>>>(sw, swT2);
    inv_fused<<<16 * 49, 512, 0, stream>>>(x, rw, swT2, sb, out);
}

// Round 7
// 329.336 us; speedup vs baseline: 3.1022x; 3.1022x over previous
//
#include <hip/hip_runtime.h>

#define C_   256
#define CR_  64
#define HW_  3136
#define W_   56
#define H_   56
#define NK_  144   // K*K*G

// span_w [144][64] -> swT2 [8][64][18]: swT2[wv][rr][kk] = sw[wv*18+kk][rr]
// Per-wave rows are 18 consecutive dwords -> scalar dwordx8 runs. 36 864 B.
__global__ __launch_bounds__(256)
void repack_sw(const float* __restrict__ sw, float* __restrict__ swT2) {
    int idx = blockIdx.x * 256 + threadIdx.x;   // 9216 total
    int k  = idx / CR_;          // 0..143
    int rr = idx - k * CR_;      // 0..63
    int wv = k / 18, kk = k - wv * 18;
    swT2[(wv * CR_ + rr) * 18 + kk] = sw[idx];
}

// One block = 64 pixels, 8 waves. Phase A: wave (rr-quarter, c-half) computes
// 16 partial r-rows over 128 channels. Phase B: wave wv computes ker rows
// [wv*18, wv*18+18) -- GEMM-accumulator idiom: RUNTIME rr loop (indexes only
// LDS/addresses), STATIC k inner loop (indexes acc). Round 3 failed w/
// runtime-indexed r[64]; round 5 failed w/ unroll-explosion spilling acc.
__global__ __launch_bounds__(512, 4)
void inv_fused(const float* __restrict__ x, const float* __restrict__ rw,
               const float* __restrict__ swT2, const float* __restrict__ span_b,
               float* __restrict__ out) {
    __shared__ float rpart[2][CR_][64];   // [c-half][rr][pixel], 32 KiB

    const int b    = blockIdx.x / 49;
    const int tile = blockIdx.x % 49;
    const int wv   = threadIdx.x >> 6;
    const int lane = threadIdx.x & 63;
    const int hw   = tile * 64 + lane;
    const int h    = hw / W_;
    const int w    = hw - h * W_;
    const float* xb = x + (size_t)b * C_ * HW_;

    // Wave-uniform SGPR values -> weight reads ride the scalar pipe.
    const int rr0 = __builtin_amdgcn_readfirstlane((wv >> 1) * 16);
    const int c0  = __builtin_amdgcn_readfirstlane((wv & 1) * 128);
    const int ch  = wv & 1;

    // ---------- phase A: partial r (16 rr-rows over 128 channels) ----------
    float racc[16];
    #pragma unroll
    for (int j = 0; j < 16; ++j) racc[j] = 0.f;

    for (int i = 0; i < 128; i += 8) {
        float xv[8];                                   // 8 loads in flight
        #pragma unroll
        for (int u = 0; u < 8; ++u)
            xv[u] = xb[(size_t)(c0 + i + u) * HW_ + hw];   // coalesced 256B/wave
        #pragma unroll
        for (int j = 0; j < 16; ++j) {
            const float* wr = rw + (size_t)(rr0 + j) * C_ + c0 + i;  // uniform -> s_load
            #pragma unroll
            for (int u = 0; u < 8; ++u)
                racc[j] += wr[u] * xv[u];              // v_fmac, SGPR weight operand
        }
    }
    #pragma unroll
    for (int j = 0; j < 16; ++j)
        rpart[ch][rr0 + j][lane] = racc[j];
    __syncthreads();

    // ---------- phase B: ker[18] = swT2[wv] . (rpart0+rpart1) + b ----------
    const int k0 = __builtin_amdgcn_readfirstlane(wv * 18);
    float acc[18];
    #pragma unroll
    for (int k = 0; k < 18; ++k) acc[k] = span_b[k0 + k];

    const float* swv = swT2 + (size_t)wv * CR_ * 18;   // uniform base
    for (int rr = 0; rr < CR_; ++rr) {                 // RUNTIME loop -- compact body
        const float rv = rpart[0][rr][lane] + rpart[1][rr][lane];  // ds_read x2
        const float* wr = swv + rr * 18;               // uniform, 18 consecutive dwords
        #pragma unroll
        for (int k = 0; k < 18; ++k)                   // STATIC acc index
            acc[k] += wr[k] * rv;
    }

    // ---------- phase C: 9-tap involution for 32 channels ----------
    const bool hok0 = (h > 0), hok2 = (h < H_ - 1);
    const bool wok0 = (w > 0), wok2 = (w < W_ - 1);

    #pragma unroll
    for (int gi = 0; gi < 2; ++gi) {
        #pragma unroll 4
        for (int cg = 0; cg < 16; ++cg) {
            const int c = (wv * 2 + gi) * 16 + cg;
            const float* xc = xb + (size_t)c * HW_ + hw;
            float a = 0.f;
            #pragma unroll
            for (int k = 0; k < 9; ++k) {
                const int di = k / 3 - 1, dj = k % 3 - 1;
                const bool ok = (di < 0 ? hok0 : (di > 0 ? hok2 : true))
                             && (dj < 0 ? wok0 : (dj > 0 ? wok2 : true));
                if (ok) a += acc[gi * 9 + k] * xc[di * W_ + dj];
            }
            out[((size_t)b * C_ + c) * HW_ + hw] = a;  // coalesced store
        }
    }
}

extern "C" void kernel_launch(void* const* d_in, const int* in_sizes, int n_in,
                              void* d_out, int out_size, void* d_ws, size_t ws_size,
                              hipStream_t stream) {
    const float* x  = (const float*)d_in[0];
    const float* rw = (const float*)d_in[1];  // [64][256]
    const float* sw = (const float*)d_in[2];  // [144][64]
    const float* sb = (const float*)d_in[3];  // [144]
    float* out  = (float*)d_out;
    float* swT2 = (float*)d_ws;               // 36 864 B

    repack_sw<<<36, 256, 0, stream>>>(sw, swT2);
    inv_fused<<<16 * 49, 512, 0, stream>>>(x, rw, swT2, sb, out);
}